// Round 5
// baseline (976.725 us; speedup 1.0000x reference)
//
#include <hip/hip_runtime.h>
#include <hip/hip_bf16.h>
#include <math.h>

// Problem constants
#define B_SZ   128
#define D_DIM  1024

// Native clang vector type: required for __builtin_nontemporal_load/store
// (HIP_vector_type float4 is a struct and is rejected by the builtin).
typedef float f32x4 __attribute__((ext_vector_type(4)));

// Workspace layout (floats)
#define WS_Q   0
#define WS_K   (131072)
#define WS_V   (262144)
#define WS_O   (393216)
#define WS_H   (524288)
#define WS_IP  (655360)
#define WS_FP  (655488)
#define WS_DEN (655616)

// Output layout (floats): h_t, C_t, n_t, m_t
#define OUT_H  0
#define OUT_C  (131072)
#define OUT_N  (134348800)
#define OUT_M  (134479872)

// ---------------------------------------------------------------------------
// Kernel 1: fused 4-matrix projection GEMM.
// O[b, j] = dot(x[b,:], W[j,:]), M=128, N=4096 (q|k|v|o), K=1024.
// Tiles: BM=64, BN=32, BK=32. 256 threads, 8 outputs/thread (2x4 micro).
// ---------------------------------------------------------------------------
__global__ __launch_bounds__(256) void gemm_proj(
    const float* __restrict__ x,
    const float* __restrict__ Wq, const float* __restrict__ Wk,
    const float* __restrict__ Wv, const float* __restrict__ Wo,
    const float* __restrict__ Wob,
    float* __restrict__ oq, float* __restrict__ okk,
    float* __restrict__ ov, float* __restrict__ oo)
{
    __shared__ float Xs[32][64];   // [k][m]
    __shared__ float Ws[32][32];   // [k][n]

    const int tid = threadIdx.x;
    const int m0 = blockIdx.y * 64;        // batch base
    const int ng = blockIdx.x * 32;        // global col base 0..4095
    const int matsel = ng >> 10;
    const int n0 = ng & 1023;
    const float* __restrict__ W =
        (matsel == 0) ? Wq : (matsel == 1) ? Wk : (matsel == 2) ? Wv : Wo;

    const int tx = tid & 7;    // col group (4 cols)
    const int ty = tid >> 3;   // row group (2 rows)

    float acc[2][4] = {{0.f,0.f,0.f,0.f},{0.f,0.f,0.f,0.f}};

    for (int kp = 0; kp < 1024; kp += 32) {
        // X panel: 64 rows x 32 k = 512 float4, 2 per thread (transposed store)
        #pragma unroll
        for (int l = 0; l < 2; ++l) {
            int f = tid + l * 256;
            int row = f >> 3, c = f & 7;
            float4 v4 = *(const float4*)&x[(m0 + row) * 1024 + kp + 4 * c];
            Xs[4*c+0][row] = v4.x; Xs[4*c+1][row] = v4.y;
            Xs[4*c+2][row] = v4.z; Xs[4*c+3][row] = v4.w;
        }
        // W panel: 32 rows x 32 k = 256 float4, 1 per thread
        {
            int row = tid >> 3, c = tid & 7;
            float4 v4 = *(const float4*)&W[(n0 + row) * 1024 + kp + 4 * c];
            Ws[4*c+0][row] = v4.x; Ws[4*c+1][row] = v4.y;
            Ws[4*c+2][row] = v4.z; Ws[4*c+3][row] = v4.w;
        }
        __syncthreads();
        #pragma unroll
        for (int k = 0; k < 32; ++k) {
            float2 xv = *(const float2*)&Xs[k][2 * ty];
            float4 wv = *(const float4*)&Ws[k][4 * tx];
            acc[0][0] += xv.x * wv.x; acc[0][1] += xv.x * wv.y;
            acc[0][2] += xv.x * wv.z; acc[0][3] += xv.x * wv.w;
            acc[1][0] += xv.y * wv.x; acc[1][1] += xv.y * wv.y;
            acc[1][2] += xv.y * wv.z; acc[1][3] += xv.y * wv.w;
        }
        __syncthreads();
    }

    #pragma unroll
    for (int r = 0; r < 2; ++r) {
        int b = m0 + 2 * ty + r;
        #pragma unroll
        for (int i2 = 0; i2 < 4; ++i2) {
            int j = n0 + 4 * tx + i2;
            float v = acc[r][i2];
            if (matsel == 0)      oq[b * 1024 + j] = v * 0.03125f;
            else if (matsel == 1) okk[b * 1024 + j] = v * 0.03125f;
            else if (matsel == 2) ov[b * 1024 + j] = v;
            else { v += Wob[j]; oo[b * 1024 + j] = 1.0f / (1.0f + expf(-v)); }
        }
    }
}

// ---------------------------------------------------------------------------
// Kernel 2: gates + n_t + denom. One block (256 thr) per batch element.
// ---------------------------------------------------------------------------
__global__ __launch_bounds__(256) void gates_kernel(
    const float* __restrict__ x, const float* __restrict__ n_prev,
    const float* __restrict__ m_prev,
    const float* __restrict__ w_i, const float* __restrict__ b_i,
    const float* __restrict__ w_f, const float* __restrict__ b_f,
    const float* __restrict__ ws_k, const float* __restrict__ ws_q,
    float* __restrict__ out_n, float* __restrict__ out_m,
    float* __restrict__ ws_ip, float* __restrict__ ws_fp,
    float* __restrict__ ws_den)
{
    const int b = blockIdx.x;
    const int t = threadIdx.x;
    const int lane = t & 63, wave = t >> 6;

    __shared__ float red[8];
    __shared__ float bc[2];

    float4 xv = ((const float4*)(x + b * 1024))[t];
    float4 wi = ((const float4*)w_i)[t];
    float4 wf = ((const float4*)w_f)[t];
    float si = xv.x*wi.x + xv.y*wi.y + xv.z*wi.z + xv.w*wi.w;
    float sf = xv.x*wf.x + xv.y*wf.y + xv.z*wf.z + xv.w*wf.w;
    #pragma unroll
    for (int off = 32; off >= 1; off >>= 1) {
        si += __shfl_down(si, off);
        sf += __shfl_down(sf, off);
    }
    if (lane == 0) { red[wave] = si; red[4 + wave] = sf; }
    __syncthreads();
    if (t == 0) {
        float zi = red[0] + red[1] + red[2] + red[3] + b_i[0];
        float zf = red[4] + red[5] + red[6] + red[7] + b_f[0];
        float mp = m_prev[b];
        float mt = fmaxf(zf + mp, zi);
        float ip = expf(zi - mt);
        float fp = expf(zf + mp - mt);
        out_m[b] = mt; ws_ip[b] = ip; ws_fp[b] = fp;
        bc[0] = ip; bc[1] = fp;
    }
    __syncthreads();
    float ip = bc[0], fp = bc[1];
    float4 np = ((const float4*)(n_prev + b * 1024))[t];
    float4 kk = ((const float4*)(ws_k + b * 1024))[t];
    float4 qq = ((const float4*)(ws_q + b * 1024))[t];
    float4 nt;
    nt.x = fp * np.x + ip * kk.x;
    nt.y = fp * np.y + ip * kk.y;
    nt.z = fp * np.z + ip * kk.z;
    nt.w = fp * np.w + ip * kk.w;
    ((float4*)(out_n + b * 1024))[t] = nt;
    float sd = nt.x*qq.x + nt.y*qq.y + nt.z*qq.z + nt.w*qq.w;
    #pragma unroll
    for (int off = 32; off >= 1; off >>= 1) sd += __shfl_down(sd, off);
    if (lane == 0) red[wave] = sd;
    __syncthreads();
    if (t == 0) {
        float d = red[0] + red[1] + red[2] + red[3];
        ws_den[b] = fmaxf(fabsf(d), 1.0f);
    }
}

// ---------------------------------------------------------------------------
// Kernel 3: C_t update + fused Cq dot + h_head.
// Wave-per-row, 2048 blocks x 256 thr = 8192 waves, 16 consecutive rows/wave.
// v2: explicit 2-row software pipeline (named cA/cB double buffer, fully
// unrolled so all indexing is compile-time — no scratch). Row rr+1's
// nontemporal loads are issued BEFORE row rr's FMA/store/shfl-reduce, so HBM
// latency hides under compute. No LDS, no __syncthreads.
// ---------------------------------------------------------------------------
__global__ __launch_bounds__(256) void cell_kernel(
    const float* __restrict__ C_prev,
    const float* __restrict__ ws_k, const float* __restrict__ ws_q,
    const float* __restrict__ ws_v, const float* __restrict__ ws_o,
    const float* __restrict__ ws_ip, const float* __restrict__ ws_fp,
    const float* __restrict__ ws_den,
    float* __restrict__ out_C, float* __restrict__ ws_h)
{
    const int t    = threadIdx.x;
    const int lane = t & 63;
    const int wave = t >> 6;
    const int wglob = blockIdx.x * 4 + wave;   // 0 .. 8191
    const int r0 = wglob * 16;                 // first global row (b*1024 + i)
    const int b  = r0 >> 10;                   // constant across the 16 rows

    const float fp   = ws_fp[b];
    const float ip   = ws_ip[b];
    const float rden = 1.0f / ws_den[b];

    // q/k fragments: lane l covers elements {4*(l+64j) .. 4*(l+64j)+3}, j=0..3
    const f32x4* qv = (const f32x4*)(ws_q + b * 1024);
    const f32x4* kv = (const f32x4*)(ws_k + b * 1024);
    f32x4 q4[4], k4[4];
    #pragma unroll
    for (int j = 0; j < 4; ++j) {
        q4[j] = qv[lane + 64 * j];
        k4[j] = kv[lane + 64 * j];
    }

    const f32x4* Cp = (const f32x4*)(C_prev + (size_t)r0 * 1024);
    f32x4*       Ct = (f32x4*)(out_C + (size_t)r0 * 1024);

    // process one row given its preloaded C fragment
    #define CELL_ROW(RR, CBUF)                                                \
    {                                                                         \
        const int row = r0 + (RR);                                            \
        const float coef = ip * ws_v[row];                                    \
        float s = 0.f;                                                        \
        _Pragma("unroll")                                                     \
        for (int j = 0; j < 4; ++j) {                                         \
            f32x4 r = fp * CBUF[j] + coef * k4[j];                            \
            __builtin_nontemporal_store(r, &Ct[(RR) * 256 + lane + 64 * j]);  \
            f32x4 d = r * q4[j];                                              \
            s += d.x + d.y + d.z + d.w;                                       \
        }                                                                     \
        _Pragma("unroll")                                                     \
        for (int off = 32; off >= 1; off >>= 1)                               \
            s += __shfl_xor(s, off);                                          \
        if (lane == 0)                                                        \
            ws_h[row] = ws_o[row] * s * rden;                                 \
    }

    f32x4 cA[4], cB[4];
    #pragma unroll
    for (int j = 0; j < 4; ++j)
        cA[j] = __builtin_nontemporal_load(&Cp[lane + 64 * j]);

    #pragma unroll
    for (int rr = 0; rr < 16; rr += 2) {
        // issue row rr+1 loads before processing row rr
        #pragma unroll
        for (int j = 0; j < 4; ++j)
            cB[j] = __builtin_nontemporal_load(&Cp[(rr + 1) * 256 + lane + 64 * j]);
        CELL_ROW(rr, cA);
        if (rr + 2 < 16) {
            #pragma unroll
            for (int j = 0; j < 4; ++j)
                cA[j] = __builtin_nontemporal_load(&Cp[(rr + 2) * 256 + lane + 64 * j]);
        }
        CELL_ROW(rr + 1, cB);
    }
    #undef CELL_ROW
}

// ---------------------------------------------------------------------------
// Kernel 4: output projection GEMM. h_t = h_head @ out_proj_w^T.
// M=128, N=1024, K=1024. Same tiling as gemm_proj.
// ---------------------------------------------------------------------------
__global__ __launch_bounds__(256) void gemm_out(
    const float* __restrict__ A,          // h_head (128 x 1024)
    const float* __restrict__ W,          // out_proj_w (1024 x 1024)
    float* __restrict__ out)              // h_t (128 x 1024)
{
    __shared__ float Xs[32][64];
    __shared__ float Ws[32][32];

    const int tid = threadIdx.x;
    const int m0 = blockIdx.y * 64;
    const int n0 = blockIdx.x * 32;
    const int tx = tid & 7;
    const int ty = tid >> 3;

    float acc[2][4] = {{0.f,0.f,0.f,0.f},{0.f,0.f,0.f,0.f}};

    for (int kp = 0; kp < 1024; kp += 32) {
        #pragma unroll
        for (int l = 0; l < 2; ++l) {
            int f = tid + l * 256;
            int row = f >> 3, c = f & 7;
            float4 v4 = *(const float4*)&A[(m0 + row) * 1024 + kp + 4 * c];
            Xs[4*c+0][row] = v4.x; Xs[4*c+1][row] = v4.y;
            Xs[4*c+2][row] = v4.z; Xs[4*c+3][row] = v4.w;
        }
        {
            int row = tid >> 3, c = tid & 7;
            float4 v4 = *(const float4*)&W[(n0 + row) * 1024 + kp + 4 * c];
            Ws[4*c+0][row] = v4.x; Ws[4*c+1][row] = v4.y;
            Ws[4*c+2][row] = v4.z; Ws[4*c+3][row] = v4.w;
        }
        __syncthreads();
        #pragma unroll
        for (int k = 0; k < 32; ++k) {
            float2 xv = *(const float2*)&Xs[k][2 * ty];
            float4 wv = *(const float4*)&Ws[k][4 * tx];
            acc[0][0] += xv.x * wv.x; acc[0][1] += xv.x * wv.y;
            acc[0][2] += xv.x * wv.z; acc[0][3] += xv.x * wv.w;
            acc[1][0] += xv.y * wv.x; acc[1][1] += xv.y * wv.y;
            acc[1][2] += xv.y * wv.z; acc[1][3] += xv.y * wv.w;
        }
        __syncthreads();
    }

    #pragma unroll
    for (int r = 0; r < 2; ++r) {
        int bb = m0 + 2 * ty + r;
        #pragma unroll
        for (int i2 = 0; i2 < 4; ++i2) {
            int j = n0 + 4 * tx + i2;
            out[bb * 1024 + j] = acc[r][i2];
        }
    }
}

// ---------------------------------------------------------------------------
extern "C" void kernel_launch(void* const* d_in, const int* in_sizes, int n_in,
                              void* d_out, int out_size, void* d_ws, size_t ws_size,
                              hipStream_t stream) {
    const float* x_t      = (const float*)d_in[0];
    const float* C_prev   = (const float*)d_in[1];
    const float* n_prev   = (const float*)d_in[2];
    const float* m_prev   = (const float*)d_in[3];
    const float* W_q      = (const float*)d_in[4];
    const float* W_k      = (const float*)d_in[5];
    const float* W_v      = (const float*)d_in[6];
    const float* w_i_w    = (const float*)d_in[7];
    const float* w_i_b    = (const float*)d_in[8];
    const float* w_f_w    = (const float*)d_in[9];
    const float* w_f_b    = (const float*)d_in[10];
    const float* W_o_w    = (const float*)d_in[11];
    const float* W_o_b    = (const float*)d_in[12];
    const float* out_proj = (const float*)d_in[13];

    float* out = (float*)d_out;
    float* ws  = (float*)d_ws;

    float* ws_q   = ws + WS_Q;
    float* ws_k   = ws + WS_K;
    float* ws_v   = ws + WS_V;
    float* ws_o   = ws + WS_O;
    float* ws_h   = ws + WS_H;
    float* ws_ip  = ws + WS_IP;
    float* ws_fp  = ws + WS_FP;
    float* ws_den = ws + WS_DEN;

    // 1. projections q,k,v,o
    gemm_proj<<<dim3(128, 2), 256, 0, stream>>>(
        x_t, W_q, W_k, W_v, W_o_w, W_o_b, ws_q, ws_k, ws_v, ws_o);

    // 2. gates, n_t, m_t, denom
    gates_kernel<<<128, 256, 0, stream>>>(
        x_t, n_prev, m_prev, w_i_w, w_i_b, w_f_w, w_f_b,
        ws_k, ws_q, out + OUT_N, out + OUT_M, ws_ip, ws_fp, ws_den);

    // 3. C_t + Cq + h_head (memory-bound main kernel)
    //    2048 blocks x 256 thr: 8192 waves x 16 rows each = 131072 rows
    cell_kernel<<<2048, 256, 0, stream>>>(
        C_prev, ws_k, ws_q, ws_v, ws_o, ws_ip, ws_fp, ws_den,
        out + OUT_C, ws_h);

    // 4. h_t = h_head @ out_proj^T
    gemm_out<<<dim3(32, 2), 256, 0, stream>>>(ws_h, out_proj, out + OUT_H);
}

// Round 8
// 951.618 us; speedup vs baseline: 1.0264x; 1.0264x over previous
//
#include <hip/hip_runtime.h>
#include <hip/hip_bf16.h>
#include <math.h>

// Problem constants
#define B_SZ   128
#define D_DIM  1024

// Native clang vector type: required for __builtin_nontemporal_load/store
// (HIP_vector_type float4 is a struct and is rejected by the builtin).
typedef float f32x4 __attribute__((ext_vector_type(4)));

// Workspace layout (floats)
#define WS_Q   0
#define WS_K   (131072)
#define WS_V   (262144)
#define WS_O   (393216)
#define WS_H   (524288)

// Output layout (floats): h_t, C_t, n_t, m_t
#define OUT_H  0
#define OUT_C  (131072)
#define OUT_N  (134348800)
#define OUT_M  (134479872)

// ---------------------------------------------------------------------------
// Kernel 1: fused 4-matrix projection GEMM.
// O[b, j] = dot(x[b,:], W[j,:]), M=128, N=4096 (q|k|v|o), K=1024.
// Tiles: BM=64, BN=32, BK=32. 256 threads, 8 outputs/thread (2x4 micro).
// v2: register-prefetch double buffer — next K-tile's global loads issue
// right after the barrier and overlap the 32-step FMA loop; the vmcnt wait
// lands at the regs->LDS store of the NEXT iteration.
// ---------------------------------------------------------------------------
__global__ __launch_bounds__(256) void gemm_proj(
    const float* __restrict__ x,
    const float* __restrict__ Wq, const float* __restrict__ Wk,
    const float* __restrict__ Wv, const float* __restrict__ Wo,
    const float* __restrict__ Wob,
    float* __restrict__ oq, float* __restrict__ okk,
    float* __restrict__ ov, float* __restrict__ oo)
{
    __shared__ float Xs[32][64];   // [k][m]
    __shared__ float Ws[32][32];   // [k][n]

    const int tid = threadIdx.x;
    const int m0 = blockIdx.y * 64;        // batch base
    const int ng = blockIdx.x * 32;        // global col base 0..4095
    const int matsel = ng >> 10;
    const int n0 = ng & 1023;
    const float* __restrict__ W =
        (matsel == 0) ? Wq : (matsel == 1) ? Wk : (matsel == 2) ? Wv : Wo;

    const int tx = tid & 7;    // col group (4 cols)
    const int ty = tid >> 3;   // row group (2 rows)

    // staging indices (constant per thread)
    const int xrow0 = tid >> 3,          xc0 = tid & 7;
    const int xrow1 = (tid + 256) >> 3,  xc1 = tid & 7;   // (tid+256)&7 == tid&7
    const int wrow  = tid >> 3,          wc  = tid & 7;

    float acc[2][4] = {{0.f,0.f,0.f,0.f},{0.f,0.f,0.f,0.f}};

    // prologue: K-tile 0 into registers
    float4 xr0 = *(const float4*)&x[(m0 + xrow0) * 1024 + 4 * xc0];
    float4 xr1 = *(const float4*)&x[(m0 + xrow1) * 1024 + 4 * xc1];
    float4 wr  = *(const float4*)&W[(n0 + wrow) * 1024 + 4 * wc];

    for (int kp = 0; kp < 1024; kp += 32) {
        // staged regs -> LDS (transposed)
        Xs[4*xc0+0][xrow0] = xr0.x; Xs[4*xc0+1][xrow0] = xr0.y;
        Xs[4*xc0+2][xrow0] = xr0.z; Xs[4*xc0+3][xrow0] = xr0.w;
        Xs[4*xc1+0][xrow1] = xr1.x; Xs[4*xc1+1][xrow1] = xr1.y;
        Xs[4*xc1+2][xrow1] = xr1.z; Xs[4*xc1+3][xrow1] = xr1.w;
        Ws[4*wc+0][wrow] = wr.x; Ws[4*wc+1][wrow] = wr.y;
        Ws[4*wc+2][wrow] = wr.z; Ws[4*wc+3][wrow] = wr.w;
        __syncthreads();

        // issue next tile's loads (overlap with FMA loop below)
        if (kp + 32 < 1024) {
            xr0 = *(const float4*)&x[(m0 + xrow0) * 1024 + kp + 32 + 4 * xc0];
            xr1 = *(const float4*)&x[(m0 + xrow1) * 1024 + kp + 32 + 4 * xc1];
            wr  = *(const float4*)&W[(n0 + wrow) * 1024 + kp + 32 + 4 * wc];
        }

        #pragma unroll
        for (int k = 0; k < 32; ++k) {
            float2 xv = *(const float2*)&Xs[k][2 * ty];
            float4 wv = *(const float4*)&Ws[k][4 * tx];
            acc[0][0] += xv.x * wv.x; acc[0][1] += xv.x * wv.y;
            acc[0][2] += xv.x * wv.z; acc[0][3] += xv.x * wv.w;
            acc[1][0] += xv.y * wv.x; acc[1][1] += xv.y * wv.y;
            acc[1][2] += xv.y * wv.z; acc[1][3] += xv.y * wv.w;
        }
        __syncthreads();
    }

    #pragma unroll
    for (int r = 0; r < 2; ++r) {
        int b = m0 + 2 * ty + r;
        #pragma unroll
        for (int i2 = 0; i2 < 4; ++i2) {
            int j = n0 + 4 * tx + i2;
            float v = acc[r][i2];
            if (matsel == 0)      oq[b * 1024 + j] = v * 0.03125f;
            else if (matsel == 1) okk[b * 1024 + j] = v * 0.03125f;
            else if (matsel == 2) ov[b * 1024 + j] = v;
            else { v += Wob[j]; oo[b * 1024 + j] = 1.0f / (1.0f + expf(-v)); }
        }
    }
}

// ---------------------------------------------------------------------------
// Kernel 2: C_t update + fused gates + fused Cq dot + h_head.
// Grid 2048 x 256 thr. Each block covers 64 consecutive rows (4 waves x 16),
// so batch b = blockIdx>>4 is uniform per block.
// Prologue recomputes the gates (ip, fp, den) per block — identical math and
// reduction order to the old gates_kernel, so numerics are bit-identical.
// Extra reads (~24 KB/block of x, w_i, w_f, n_prev, k, q) are L2 hits shared
// by the 16 blocks of each batch element. Block bid%16==0 writes n_t / m_t.
// Main loop: wave-per-row, 2-row software pipeline, nontemporal C stream.
// ---------------------------------------------------------------------------
__global__ __launch_bounds__(256) void cell_kernel(
    const float* __restrict__ x, const float* __restrict__ n_prev,
    const float* __restrict__ m_prev,
    const float* __restrict__ w_i, const float* __restrict__ b_i,
    const float* __restrict__ w_f, const float* __restrict__ b_f,
    const float* __restrict__ C_prev,
    const float* __restrict__ ws_k, const float* __restrict__ ws_q,
    const float* __restrict__ ws_v, const float* __restrict__ ws_o,
    float* __restrict__ out_C, float* __restrict__ out_n,
    float* __restrict__ out_m, float* __restrict__ ws_h)
{
    const int t    = threadIdx.x;
    const int lane = t & 63;
    const int wave = t >> 6;
    const int b    = blockIdx.x >> 4;          // uniform per block
    const bool elected = (blockIdx.x & 15) == 0;

    __shared__ float red[8];
    __shared__ float bc[4];

    // ---- gates prologue (same math/order as the old gates_kernel) ----
    {
        float4 xv = ((const float4*)(x + b * 1024))[t];
        float4 wi = ((const float4*)w_i)[t];
        float4 wf = ((const float4*)w_f)[t];
        float si = xv.x*wi.x + xv.y*wi.y + xv.z*wi.z + xv.w*wi.w;
        float sf = xv.x*wf.x + xv.y*wf.y + xv.z*wf.z + xv.w*wf.w;
        #pragma unroll
        for (int off = 32; off >= 1; off >>= 1) {
            si += __shfl_down(si, off);
            sf += __shfl_down(sf, off);
        }
        if (lane == 0) { red[wave] = si; red[4 + wave] = sf; }
        __syncthreads();
        if (t == 0) {
            float zi = red[0] + red[1] + red[2] + red[3] + b_i[0];
            float zf = red[4] + red[5] + red[6] + red[7] + b_f[0];
            float mp = m_prev[b];
            float mt = fmaxf(zf + mp, zi);
            float ipv = expf(zi - mt);
            float fpv = expf(zf + mp - mt);
            bc[0] = ipv; bc[1] = fpv;
            if (elected) out_m[b] = mt;
        }
        __syncthreads();
        float ipv = bc[0], fpv = bc[1];
        float4 np = ((const float4*)(n_prev + b * 1024))[t];
        float4 kk = ((const float4*)(ws_k + b * 1024))[t];
        float4 qq = ((const float4*)(ws_q + b * 1024))[t];
        float4 nt;
        nt.x = fpv * np.x + ipv * kk.x;
        nt.y = fpv * np.y + ipv * kk.y;
        nt.z = fpv * np.z + ipv * kk.z;
        nt.w = fpv * np.w + ipv * kk.w;
        if (elected) ((float4*)(out_n + b * 1024))[t] = nt;
        float sd = nt.x*qq.x + nt.y*qq.y + nt.z*qq.z + nt.w*qq.w;
        #pragma unroll
        for (int off = 32; off >= 1; off >>= 1) sd += __shfl_down(sd, off);
        if (lane == 0) red[wave] = sd;
        __syncthreads();
        if (t == 0) {
            float d = red[0] + red[1] + red[2] + red[3];
            bc[2] = 1.0f / fmaxf(fabsf(d), 1.0f);
        }
        __syncthreads();
    }

    const float ip   = bc[0];
    const float fp   = bc[1];
    const float rden = bc[2];

    // ---- main loop: wave-per-row, 16 rows/wave, 2-row pipeline ----
    const int wglob = blockIdx.x * 4 + wave;   // 0 .. 8191
    const int r0 = wglob * 16;                 // first global row (b*1024 + i)

    // q/k fragments: lane l covers elements {4*(l+64j) .. 4*(l+64j)+3}, j=0..3
    const f32x4* qv = (const f32x4*)(ws_q + b * 1024);
    const f32x4* kv = (const f32x4*)(ws_k + b * 1024);
    f32x4 q4[4], k4[4];
    #pragma unroll
    for (int j = 0; j < 4; ++j) {
        q4[j] = qv[lane + 64 * j];
        k4[j] = kv[lane + 64 * j];
    }

    const f32x4* Cp = (const f32x4*)(C_prev + (size_t)r0 * 1024);
    f32x4*       Ct = (f32x4*)(out_C + (size_t)r0 * 1024);

    #define CELL_ROW(RR, CBUF)                                                \
    {                                                                         \
        const int row = r0 + (RR);                                            \
        const float coef = ip * ws_v[row];                                    \
        float s = 0.f;                                                        \
        _Pragma("unroll")                                                     \
        for (int j = 0; j < 4; ++j) {                                         \
            f32x4 r = fp * CBUF[j] + coef * k4[j];                            \
            __builtin_nontemporal_store(r, &Ct[(RR) * 256 + lane + 64 * j]);  \
            f32x4 d = r * q4[j];                                              \
            s += d.x + d.y + d.z + d.w;                                       \
        }                                                                     \
        _Pragma("unroll")                                                     \
        for (int off = 32; off >= 1; off >>= 1)                               \
            s += __shfl_xor(s, off);                                          \
        if (lane == 0)                                                        \
            ws_h[row] = ws_o[row] * s * rden;                                 \
    }

    f32x4 cA[4], cB[4];
    #pragma unroll
    for (int j = 0; j < 4; ++j)
        cA[j] = __builtin_nontemporal_load(&Cp[lane + 64 * j]);

    #pragma unroll
    for (int rr = 0; rr < 16; rr += 2) {
        #pragma unroll
        for (int j = 0; j < 4; ++j)
            cB[j] = __builtin_nontemporal_load(&Cp[(rr + 1) * 256 + lane + 64 * j]);
        CELL_ROW(rr, cA);
        if (rr + 2 < 16) {
            #pragma unroll
            for (int j = 0; j < 4; ++j)
                cA[j] = __builtin_nontemporal_load(&Cp[(rr + 2) * 256 + lane + 64 * j]);
        }
        CELL_ROW(rr + 1, cB);
    }
    #undef CELL_ROW
}

// ---------------------------------------------------------------------------
// Kernel 3: output projection GEMM. h_t = h_head @ out_proj_w^T.
// M=128, N=1024, K=1024. v2: BM=32 (grid 32x4 = 128 blocks, 2x the CUs busy)
// + register-prefetch double buffer. 256 thr, 4 outputs/thread (1 row x 4 cols).
// ---------------------------------------------------------------------------
__global__ __launch_bounds__(256) void gemm_out(
    const float* __restrict__ A,          // h_head (128 x 1024)
    const float* __restrict__ W,          // out_proj_w (1024 x 1024)
    float* __restrict__ out)              // h_t (128 x 1024)
{
    __shared__ float Xs[32][32];   // [k][m]
    __shared__ float Ws[32][32];   // [k][n]

    const int tid = threadIdx.x;
    const int m0 = blockIdx.y * 32;
    const int n0 = blockIdx.x * 32;
    const int tx = tid & 7;        // col group (4 cols)
    const int ty = tid >> 3;       // row (0..31)

    const int xrow = tid >> 3, xc = tid & 7;
    const int wrow = tid >> 3, wc = tid & 7;

    float acc[4] = {0.f, 0.f, 0.f, 0.f};

    // prologue: K-tile 0 into registers
    float4 xr = *(const float4*)&A[(m0 + xrow) * 1024 + 4 * xc];
    float4 wr = *(const float4*)&W[(n0 + wrow) * 1024 + 4 * wc];

    for (int kp = 0; kp < 1024; kp += 32) {
        Xs[4*xc+0][xrow] = xr.x; Xs[4*xc+1][xrow] = xr.y;
        Xs[4*xc+2][xrow] = xr.z; Xs[4*xc+3][xrow] = xr.w;
        Ws[4*wc+0][wrow] = wr.x; Ws[4*wc+1][wrow] = wr.y;
        Ws[4*wc+2][wrow] = wr.z; Ws[4*wc+3][wrow] = wr.w;
        __syncthreads();

        if (kp + 32 < 1024) {
            xr = *(const float4*)&A[(m0 + xrow) * 1024 + kp + 32 + 4 * xc];
            wr = *(const float4*)&W[(n0 + wrow) * 1024 + kp + 32 + 4 * wc];
        }

        #pragma unroll
        for (int k = 0; k < 32; ++k) {
            float  xv = Xs[k][ty];
            float4 wv = *(const float4*)&Ws[k][4 * tx];
            acc[0] += xv * wv.x; acc[1] += xv * wv.y;
            acc[2] += xv * wv.z; acc[3] += xv * wv.w;
        }
        __syncthreads();
    }

    const int bb = m0 + ty;
    #pragma unroll
    for (int i2 = 0; i2 < 4; ++i2)
        out[bb * 1024 + n0 + 4 * tx + i2] = acc[i2];
}

// ---------------------------------------------------------------------------
extern "C" void kernel_launch(void* const* d_in, const int* in_sizes, int n_in,
                              void* d_out, int out_size, void* d_ws, size_t ws_size,
                              hipStream_t stream) {
    const float* x_t      = (const float*)d_in[0];
    const float* C_prev   = (const float*)d_in[1];
    const float* n_prev   = (const float*)d_in[2];
    const float* m_prev   = (const float*)d_in[3];
    const float* W_q      = (const float*)d_in[4];
    const float* W_k      = (const float*)d_in[5];
    const float* W_v      = (const float*)d_in[6];
    const float* w_i_w    = (const float*)d_in[7];
    const float* w_i_b    = (const float*)d_in[8];
    const float* w_f_w    = (const float*)d_in[9];
    const float* w_f_b    = (const float*)d_in[10];
    const float* W_o_w    = (const float*)d_in[11];
    const float* W_o_b    = (const float*)d_in[12];
    const float* out_proj = (const float*)d_in[13];

    float* out = (float*)d_out;
    float* ws  = (float*)d_ws;

    float* ws_q = ws + WS_Q;
    float* ws_k = ws + WS_K;
    float* ws_v = ws + WS_V;
    float* ws_o = ws + WS_O;
    float* ws_h = ws + WS_H;

    // 1. projections q,k,v,o
    gemm_proj<<<dim3(128, 2), 256, 0, stream>>>(
        x_t, W_q, W_k, W_v, W_o_w, W_o_b, ws_q, ws_k, ws_v, ws_o);

    // 2. fused gates + C_t + Cq + h_head (memory-bound main kernel)
    cell_kernel<<<2048, 256, 0, stream>>>(
        x_t, n_prev, m_prev, w_i_w, w_i_b, w_f_w, w_f_b,
        C_prev, ws_k, ws_q, ws_v, ws_o,
        out + OUT_C, out + OUT_N, out + OUT_M, ws_h);

    // 3. h_t = h_head @ out_proj^T
    gemm_out<<<dim3(32, 4), 256, 0, stream>>>(ws_h, out_proj, out + OUT_H);
}